// Round 3
// baseline (914.525 us; speedup 1.0000x reference)
//
#include <hip/hip_runtime.h>

// Markonv: out[b,n,p] = sum_{l,ij} x[b,i,p+l]*x[b,j,p+l+1] * W[l,i,j,n]
// B=128, C=4, L=10000, K=20, N=128, stride=1, P=9980.
// v4: kill the W-fragment spill. v2/v3 ran with VGPR_Count=68 < the 80 VGPRs
// the bfr[20] array needs => allocator spilled W to scratch under the
// launch_bounds(256,3) cap of ~170; inner loop was doing 40 scratch reloads
// per tile (WRITE_SIZE excess 106MB = spill traffic). Now launch_bounds(256,2)
// (VGPR cap 256; LDS 50.6KB allows exactly 2 WGs/CU anyway) and bfr loaded
// after the staging barriers (short live range). Mega-stage structure kept:
// stage 768-position span once, build all 787 pair rows once, 12 barrier-free
// MFMA tiles.
// Roofline: max(654MB writes ~110-160us, LDS ~60us, MFMA ~42us) => ~200us.

#define B_    128
#define C_    4
#define L_    10000
#define K_    20
#define N_    128
#define P_    9980            // floor((L-1-K)/1)+1
#define MT    64              // output positions per tile
#define TPG   12              // tiles per workgroup
#define GRPS  13              // 13*12*64 = 9984 >= 9980
#define SPAN  (TPG * MT)      // 768 positions per WG
#define ROWS  (SPAN + K_ - 1) // 787 pair rows
#define XSL   (ROWS + 1)      // 788 x positions per channel
#define PSTR  24              // pair row stride in shorts (48 B -> 4-way banks)

typedef float  f32x16 __attribute__((ext_vector_type(16)));
typedef __bf16 bf16x8 __attribute__((ext_vector_type(8)));
typedef unsigned short u16x8 __attribute__((ext_vector_type(8)));

static __device__ __forceinline__ unsigned short f2bf(float f) {
  union { float f; unsigned u; } v; v.f = f;
  unsigned r = (v.u + 0x7fffu + ((v.u >> 16) & 1u)) >> 16;
  return (unsigned short)r;
}

// Repack W[l][i][j][n] fp32 -> Wb[l][n][ij] bf16 (A-fragment friendly: 16
// contiguous bf16 per (l,n) row = one 16B half per lane-half).
__global__ void convW_kernel(const float* __restrict__ W,
                             unsigned short* __restrict__ Wb) {
  int idx = blockIdx.x * 256 + threadIdx.x;          // [l][n][ij]
  if (idx < K_ * N_ * 16) {
    int ij = idx & 15, n = (idx >> 4) & (N_ - 1), l = idx >> 11;
    Wb[idx] = f2bf(W[(l * 16 + ij) * N_ + n]);
  }
}

template <int USE_GATHER>
__launch_bounds__(256, 2)
__global__ void markonv_kernel(const float* __restrict__ x,
                               const unsigned short* __restrict__ Wb,
                               const float* __restrict__ Wf,
                               float* __restrict__ out) {
  __shared__ __align__(16) float xs[C_][XSL + 4];                // 12.7 KB
  __shared__ __align__(16) unsigned short pairLds[ROWS * PSTR];  // 37.8 KB

  const int tid  = threadIdx.x;
  const int lane = tid & 63;
  const int wid  = tid >> 6;        // wave owns n-block: n = wid*32 + nl
  const int h    = lane >> 5;       // k-half
  const int nl   = lane & 31;
  const int b    = blockIdx.y;
  const int grp  = blockIdx.x;
  const int t0g  = grp * SPAN;

  // ---- phase A: stage the whole span, wave wid = channel wid, float4 ----
  {
    const float* xrow = x + (size_t)(b * C_ + wid) * L_;
    #pragma unroll 1
    for (int v = lane; v < XSL / 4; v += 64) {          // 197 float4 chunks
      int t = t0g + 4 * v;
      float4 val;
      if (t + 3 < L_) {
        val = *(const float4*)(xrow + t);               // t0g%768==0 -> aligned
      } else {
        val.x = (t + 0 < L_) ? xrow[t + 0] : 0.f;
        val.y = (t + 1 < L_) ? xrow[t + 1] : 0.f;
        val.z = (t + 2 < L_) ? xrow[t + 2] : 0.f;
        val.w = (t + 3 < L_) ? xrow[t + 3] : 0.f;
      }
      *(float4*)&xs[wid][4 * v] = val;
    }
  }
  __syncthreads();

  // ---- phase B: build ALL pair rows: pair[r][i*4+j] = x[i][r]*x[j][r+1] ----
  // 1574 half-row tasks over 256 threads; one 16B LDS store per task
  #pragma unroll 1
  for (int task = tid; task < ROWS * 2; task += 256) {
    int r = task >> 1, half = task & 1;
    float x0 = xs[2 * half + 0][r], x1 = xs[2 * half + 1][r];
    float y0 = xs[0][r + 1], y1 = xs[1][r + 1];
    float y2 = xs[2][r + 1], y3 = xs[3][r + 1];
    u16x8 u;
    u[0] = f2bf(x0 * y0); u[1] = f2bf(x0 * y1);
    u[2] = f2bf(x0 * y2); u[3] = f2bf(x0 * y3);
    u[4] = f2bf(x1 * y0); u[5] = f2bf(x1 * y1);
    u[6] = f2bf(x1 * y2); u[7] = f2bf(x1 * y3);
    *(u16x8*)&pairLds[r * PSTR + 8 * half] = u;
  }
  __syncthreads();

  // ---- W fragments (A-operand), loaded AFTER staging so the 80-VGPR array
  //      has a short live range: 20 x 4 VGPR, resident under the 256 cap ----
  // bfr[l]: lane holds W[l][k=8h+j][n = wid*32 + nl], j=0..7
  bf16x8 bfr[K_];
  if (USE_GATHER) {
    #pragma unroll
    for (int l = 0; l < K_; ++l) {
      int n = wid * 32 + nl;
      u16x8 u;
      #pragma unroll
      for (int j = 0; j < 8; ++j)
        u[j] = f2bf(Wf[(l * 16 + 8 * h + j) * N_ + n]);
      bfr[l] = __builtin_bit_cast(bf16x8, u);
    }
  } else {
    #pragma unroll
    for (int l = 0; l < K_; ++l) {
      int n = wid * 32 + nl;
      bfr[l] = __builtin_bit_cast(bf16x8,
          *(const u16x8*)(Wb + ((l * N_ + n) * 16 + 8 * h)));
    }
  }

  // ---- phase C: 12 tiles, NO barriers. W-stationary, pair read-only ----
  #pragma unroll 1
  for (int it = 0; it < TPG; ++it) {
    const int t0 = t0g + it * MT;
    f32x16 acc0, acc1;
    #pragma unroll
    for (int i = 0; i < 16; ++i) { acc0[i] = 0.f; acc1[i] = 0.f; }

    const int rbase = it * MT + nl;
    #pragma unroll
    for (int l = 0; l < K_; ++l) {
      bf16x8 p0 = __builtin_bit_cast(bf16x8,
          *(const u16x8*)&pairLds[(rbase + l) * PSTR + 8 * h]);
      bf16x8 p1 = __builtin_bit_cast(bf16x8,
          *(const u16x8*)&pairLds[(rbase + 32 + l) * PSTR + 8 * h]);
      acc0 = __builtin_amdgcn_mfma_f32_32x32x16_bf16(bfr[l], p0, acc0, 0, 0, 0);
      acc1 = __builtin_amdgcn_mfma_f32_32x32x16_bf16(bfr[l], p1, acc1, 0, 0, 0);
    }

    // epilogue: D col = lane -> position; 16 regs = 16 n-rows. r-major order
    // so each n-row gets 256B contiguous from this wave (L2 line merging).
    float* base = out + (size_t)(b * N_ + wid * 32 + 4 * h) * P_;
    const int p = t0 + nl, p2 = t0 + 32 + nl;
    #pragma unroll
    for (int r = 0; r < 16; ++r) {
      int m = (r & 3) + 8 * (r >> 2);        // n offset within wave's block
      float* orow = base + (size_t)m * P_;
      if (p < P_)  __builtin_nontemporal_store(acc0[r], orow + p);
      if (p2 < P_) __builtin_nontemporal_store(acc1[r], orow + p2);
    }
  }
}

extern "C" void kernel_launch(void* const* d_in, const int* in_sizes, int n_in,
                              void* d_out, int out_size, void* d_ws, size_t ws_size,
                              hipStream_t stream) {
  const float* x  = (const float*)d_in[0];
  const float* W  = (const float*)d_in[1];
  float* out      = (float*)d_out;

  const size_t wbBytes = (size_t)K_ * N_ * 16 * sizeof(unsigned short); // 80 KB
  int useGather = (ws_size < wbBytes || d_ws == nullptr) ? 1 : 0;
  unsigned short* Wb = (unsigned short*)d_ws;

  if (!useGather) {
    convW_kernel<<<dim3((K_ * N_ * 16 + 255) / 256), dim3(256), 0, stream>>>(W, Wb);
    markonv_kernel<0><<<dim3(GRPS, B_), dim3(256), 0, stream>>>(x, Wb, W, out);
  } else {
    markonv_kernel<1><<<dim3(GRPS, B_), dim3(256), 0, stream>>>(x, Wb, W, out);
  }
}

// Round 4
// 912.873 us; speedup vs baseline: 1.0018x; 1.0018x over previous
//
#include <hip/hip_runtime.h>

// Markonv: out[b,n,p] = sum_{l,ij} x[b,i,p+l]*x[b,j,p+l+1] * W[l,i,j,n]
// B=128, C=4, L=10000, K=20, N=128, stride=1, P=9980.
// v5: v4 structure (mega-stage, bfr loaded AFTER staging barriers) but at
// __launch_bounds__(256,3): VGPR cap ~170 >= demand ~150 (bfr 80 + acc 32 +
// temps), LDS 50.4KB*3 = 151KB <= 160KB -> 3 WGs/CU. v4's (256,2) fixed the
// W-fragment spill but gave back 1/3 occupancy = net neutral. The spill is
// poison beyond load cost: global W reloads in phase C share vmcnt with the
// outstanding NT stores, so each pre-MFMA waitcnt drains the store queue to
// HBM (~20x/tile). Resident bfr => phase C is pure lgkmcnt+MFMA+unwaited
// stores.
// Roofline: max(654MB writes ~105-160us, LDS ~62us, MFMA ~42us) => ~150-200us.

#define B_    128
#define C_    4
#define L_    10000
#define K_    20
#define N_    128
#define P_    9980            // floor((L-1-K)/1)+1
#define MT    64              // output positions per tile
#define TPG   12              // tiles per workgroup
#define GRPS  13              // 13*12*64 = 9984 >= 9980
#define SPAN  (TPG * MT)      // 768 positions per WG
#define ROWS  (SPAN + K_ - 1) // 787 pair rows
#define XSL   (ROWS + 1)      // 788 x positions per channel
#define PSTR  24              // pair row stride in shorts (48 B -> 4-way banks)

typedef float  f32x16 __attribute__((ext_vector_type(16)));
typedef __bf16 bf16x8 __attribute__((ext_vector_type(8)));
typedef unsigned short u16x8 __attribute__((ext_vector_type(8)));

static __device__ __forceinline__ unsigned short f2bf(float f) {
  union { float f; unsigned u; } v; v.f = f;
  unsigned r = (v.u + 0x7fffu + ((v.u >> 16) & 1u)) >> 16;
  return (unsigned short)r;
}

// Repack W[l][i][j][n] fp32 -> Wb[l][n][ij] bf16 (A-fragment friendly: 16
// contiguous bf16 per (l,n) row = one 16B half per lane-half).
__global__ void convW_kernel(const float* __restrict__ W,
                             unsigned short* __restrict__ Wb) {
  int idx = blockIdx.x * 256 + threadIdx.x;          // [l][n][ij]
  if (idx < K_ * N_ * 16) {
    int ij = idx & 15, n = (idx >> 4) & (N_ - 1), l = idx >> 11;
    Wb[idx] = f2bf(W[(l * 16 + ij) * N_ + n]);
  }
}

template <int USE_GATHER>
__launch_bounds__(256, 3)
__global__ void markonv_kernel(const float* __restrict__ x,
                               const unsigned short* __restrict__ Wb,
                               const float* __restrict__ Wf,
                               float* __restrict__ out) {
  __shared__ __align__(16) float xs[C_][XSL + 4];                // 12.7 KB
  __shared__ __align__(16) unsigned short pairLds[ROWS * PSTR];  // 37.8 KB

  const int tid  = threadIdx.x;
  const int lane = tid & 63;
  const int wid  = tid >> 6;        // wave owns n-block: n = wid*32 + nl
  const int h    = lane >> 5;       // k-half
  const int nl   = lane & 31;
  const int b    = blockIdx.y;
  const int grp  = blockIdx.x;
  const int t0g  = grp * SPAN;

  // ---- phase A: stage the whole span, wave wid = channel wid, float4 ----
  {
    const float* xrow = x + (size_t)(b * C_ + wid) * L_;
    #pragma unroll 1
    for (int v = lane; v < XSL / 4; v += 64) {          // 197 float4 chunks
      int t = t0g + 4 * v;
      float4 val;
      if (t + 3 < L_) {
        val = *(const float4*)(xrow + t);               // t0g%768==0 -> aligned
      } else {
        val.x = (t + 0 < L_) ? xrow[t + 0] : 0.f;
        val.y = (t + 1 < L_) ? xrow[t + 1] : 0.f;
        val.z = (t + 2 < L_) ? xrow[t + 2] : 0.f;
        val.w = (t + 3 < L_) ? xrow[t + 3] : 0.f;
      }
      *(float4*)&xs[wid][4 * v] = val;
    }
  }
  __syncthreads();

  // ---- phase B: build ALL pair rows: pair[r][i*4+j] = x[i][r]*x[j][r+1] ----
  // 1574 half-row tasks over 256 threads; one 16B LDS store per task
  #pragma unroll 1
  for (int task = tid; task < ROWS * 2; task += 256) {
    int r = task >> 1, half = task & 1;
    float x0 = xs[2 * half + 0][r], x1 = xs[2 * half + 1][r];
    float y0 = xs[0][r + 1], y1 = xs[1][r + 1];
    float y2 = xs[2][r + 1], y3 = xs[3][r + 1];
    u16x8 u;
    u[0] = f2bf(x0 * y0); u[1] = f2bf(x0 * y1);
    u[2] = f2bf(x0 * y2); u[3] = f2bf(x0 * y3);
    u[4] = f2bf(x1 * y0); u[5] = f2bf(x1 * y1);
    u[6] = f2bf(x1 * y2); u[7] = f2bf(x1 * y3);
    *(u16x8*)&pairLds[r * PSTR + 8 * half] = u;
  }
  __syncthreads();

  // ---- W fragments (A-operand), loaded AFTER staging so the 80-VGPR array
  //      has a short live range; must stay resident through phase C ----
  // bfr[l]: lane holds W[l][k=8h+j][n = wid*32 + nl], j=0..7
  bf16x8 bfr[K_];
  {
    const int n = wid * 32 + nl;
    if (USE_GATHER) {
      #pragma unroll
      for (int l = 0; l < K_; ++l) {
        u16x8 u;
        #pragma unroll
        for (int j = 0; j < 8; ++j)
          u[j] = f2bf(Wf[(l * 16 + 8 * h + j) * N_ + n]);
        bfr[l] = __builtin_bit_cast(bf16x8, u);
      }
    } else {
      #pragma unroll
      for (int l = 0; l < K_; ++l)
        bfr[l] = __builtin_bit_cast(bf16x8,
            *(const u16x8*)(Wb + ((l * N_ + n) * 16 + 8 * h)));
    }
  }

  // ---- phase C: 12 tiles, NO barriers. W-stationary, pair read-only.
  //      No global loads here: ds_read (lgkmcnt) never drains the NT-store
  //      queue (vmcnt), so stores stream out while MFMA proceeds ----
  #pragma unroll 1
  for (int it = 0; it < TPG; ++it) {
    const int t0 = t0g + it * MT;
    f32x16 acc0, acc1;
    #pragma unroll
    for (int i = 0; i < 16; ++i) { acc0[i] = 0.f; acc1[i] = 0.f; }

    const int rbase = it * MT + nl;
    #pragma unroll
    for (int l = 0; l < K_; ++l) {
      bf16x8 p0 = __builtin_bit_cast(bf16x8,
          *(const u16x8*)&pairLds[(rbase + l) * PSTR + 8 * h]);
      bf16x8 p1 = __builtin_bit_cast(bf16x8,
          *(const u16x8*)&pairLds[(rbase + 32 + l) * PSTR + 8 * h]);
      acc0 = __builtin_amdgcn_mfma_f32_32x32x16_bf16(bfr[l], p0, acc0, 0, 0, 0);
      acc1 = __builtin_amdgcn_mfma_f32_32x32x16_bf16(bfr[l], p1, acc1, 0, 0, 0);
    }

    // epilogue: D col = lane -> position; 16 regs = 16 n-rows. r-major order
    // so each n-row gets 256B contiguous from this wave (L2 line merging).
    float* base = out + (size_t)(b * N_ + wid * 32 + 4 * h) * P_;
    const int p = t0 + nl, p2 = t0 + 32 + nl;
    #pragma unroll
    for (int r = 0; r < 16; ++r) {
      int m = (r & 3) + 8 * (r >> 2);        // n offset within wave's block
      float* orow = base + (size_t)m * P_;
      if (p < P_)  __builtin_nontemporal_store(acc0[r], orow + p);
      if (p2 < P_) __builtin_nontemporal_store(acc1[r], orow + p2);
    }
  }
}

extern "C" void kernel_launch(void* const* d_in, const int* in_sizes, int n_in,
                              void* d_out, int out_size, void* d_ws, size_t ws_size,
                              hipStream_t stream) {
  const float* x  = (const float*)d_in[0];
  const float* W  = (const float*)d_in[1];
  float* out      = (float*)d_out;

  const size_t wbBytes = (size_t)K_ * N_ * 16 * sizeof(unsigned short); // 80 KB
  int useGather = (ws_size < wbBytes || d_ws == nullptr) ? 1 : 0;
  unsigned short* Wb = (unsigned short*)d_ws;

  if (!useGather) {
    convW_kernel<<<dim3((K_ * N_ * 16 + 255) / 256), dim3(256), 0, stream>>>(W, Wb);
    markonv_kernel<0><<<dim3(GRPS, B_), dim3(256), 0, stream>>>(x, Wb, W, out);
  } else {
    markonv_kernel<1><<<dim3(GRPS, B_), dim3(256), 0, stream>>>(x, Wb, W, out);
  }
}